// Round 1
// baseline (24001.076 us; speedup 1.0000x reference)
//
#include <hip/hip_runtime.h>
#include <hip/hip_bf16.h>
#include <math.h>

// Problem constants (Encoder, D=768, H=12, L=12)
#define BB 4
#define TT 1024
#define DD 768
#define HH 12
#define DH 64
#define FF2 3072
#define NL 12
#define MM (BB * TT)            // 4096 rows
#define SCALE 0.03608439182435161f   // 768^-0.5
#define LN_EPS 1e-5f

// ---------------------------------------------------------------------------
// LayerNorm: one block per row of 768, 256 threads (3 elems/thread)
// ---------------------------------------------------------------------------
__global__ __launch_bounds__(256) void ln_kernel(const float* __restrict__ x,
                                                 const float* __restrict__ g,
                                                 const float* __restrict__ b,
                                                 float* __restrict__ out) {
    const int r = blockIdx.x;
    const int tid = threadIdx.x;
    const float* xr = x + (size_t)r * DD;
    float v0 = xr[tid], v1 = xr[tid + 256], v2 = xr[tid + 512];

    __shared__ float red[256];
    red[tid] = v0 + v1 + v2;
    __syncthreads();
    for (int off = 128; off > 0; off >>= 1) {
        if (tid < off) red[tid] += red[tid + off];
        __syncthreads();
    }
    float mu = red[0] * (1.0f / DD);
    __syncthreads();

    float d0 = v0 - mu, d1 = v1 - mu, d2 = v2 - mu;
    red[tid] = d0 * d0 + d1 * d1 + d2 * d2;
    __syncthreads();
    for (int off = 128; off > 0; off >>= 1) {
        if (tid < off) red[tid] += red[tid + off];
        __syncthreads();
    }
    float rstd = rsqrtf(red[0] * (1.0f / DD) + LN_EPS);

    float* outr = out + (size_t)r * DD;
    outr[tid]       = d0 * rstd * g[tid]       + b[tid];
    outr[tid + 256] = d1 * rstd * g[tid + 256] + b[tid + 256];
    outr[tid + 512] = d2 * rstd * g[tid + 512] + b[tid + 512];
}

// ---------------------------------------------------------------------------
// Tiled fp32 GEMM: C[M,N] = epi(A[M,K] @ W[K,N] + bias[N] (+ res[M,N]))
// 64x64 tile, BK=16, 256 threads, 4x4 micro-tile per thread.
// EPI: 0 = bias only, 1 = bias + residual add, 2 = bias + exact gelu
// ---------------------------------------------------------------------------
__device__ __forceinline__ float gelu_exact(float x) {
    return 0.5f * x * (1.0f + erff(x * 0.70710678118654752440f));
}

template <int EPI>
__global__ __launch_bounds__(256) void gemm_kernel(const float* __restrict__ A,
                                                   const float* __restrict__ W,
                                                   const float* __restrict__ bias,
                                                   const float* __restrict__ res,
                                                   float* __restrict__ C,
                                                   int M, int N, int K) {
    __shared__ float As[16][65];               // As[k][m], +1 pad
    __shared__ __align__(16) float Bs[16][64]; // Bs[k][n]

    const int tid = threadIdx.x;
    const int m0 = blockIdx.y * 64;
    const int n0 = blockIdx.x * 64;
    const int tx = tid & 15;    // n micro-tile
    const int ty = tid >> 4;    // m micro-tile

    // global-load assignments
    const int am = tid >> 2;          // 0..63 (row within A tile)
    const int ak = (tid & 3) * 4;     // 0,4,8,12
    const int wk = tid >> 4;          // 0..15 (row within W tile)
    const int wn = (tid & 15) * 4;    // 0..60

    const float* Aptr = A + (size_t)(m0 + am) * K + ak;
    const float* Wptr = W + (size_t)wk * N + (n0 + wn);

    float acc[4][4] = {};

    for (int k0 = 0; k0 < K; k0 += 16) {
        float4 a4 = *(const float4*)(Aptr + k0);
        float4 w4 = *(const float4*)(Wptr + (size_t)k0 * N);

        As[ak + 0][am] = a4.x;
        As[ak + 1][am] = a4.y;
        As[ak + 2][am] = a4.z;
        As[ak + 3][am] = a4.w;
        *(float4*)(&Bs[wk][wn]) = w4;
        __syncthreads();

#pragma unroll
        for (int k = 0; k < 16; ++k) {
            float a0 = As[k][ty * 4 + 0];
            float a1 = As[k][ty * 4 + 1];
            float a2 = As[k][ty * 4 + 2];
            float a3 = As[k][ty * 4 + 3];
            float4 b4 = *(const float4*)(&Bs[k][tx * 4]);
            acc[0][0] += a0 * b4.x; acc[0][1] += a0 * b4.y; acc[0][2] += a0 * b4.z; acc[0][3] += a0 * b4.w;
            acc[1][0] += a1 * b4.x; acc[1][1] += a1 * b4.y; acc[1][2] += a1 * b4.z; acc[1][3] += a1 * b4.w;
            acc[2][0] += a2 * b4.x; acc[2][1] += a2 * b4.y; acc[2][2] += a2 * b4.z; acc[2][3] += a2 * b4.w;
            acc[3][0] += a3 * b4.x; acc[3][1] += a3 * b4.y; acc[3][2] += a3 * b4.z; acc[3][3] += a3 * b4.w;
        }
        __syncthreads();
    }

    const int n = n0 + tx * 4;
    float4 bi = *(const float4*)(bias + n);
#pragma unroll
    for (int i = 0; i < 4; ++i) {
        const int m = m0 + ty * 4 + i;
        float4 c;
        c.x = acc[i][0] + bi.x;
        c.y = acc[i][1] + bi.y;
        c.z = acc[i][2] + bi.z;
        c.w = acc[i][3] + bi.w;
        if (EPI == 1) {
            float4 r = *(const float4*)(res + (size_t)m * N + n);
            c.x += r.x; c.y += r.y; c.z += r.z; c.w += r.w;
        }
        if (EPI == 2) {
            c.x = gelu_exact(c.x);
            c.y = gelu_exact(c.y);
            c.z = gelu_exact(c.z);
            c.w = gelu_exact(c.w);
        }
        *(float4*)(C + (size_t)m * N + n) = c;
    }
}

// ---------------------------------------------------------------------------
// Attention (quirky: scores = q . v): one block per (b, h, query-row l).
// scores row (1024) in LDS -> softmax -> ctx = probs @ V_slice.
// ---------------------------------------------------------------------------
__global__ __launch_bounds__(256) void attn_kernel(const float* __restrict__ Q,
                                                   const float* __restrict__ V,
                                                   float* __restrict__ Ctx) {
    const int gid = blockIdx.x;             // ((b*H)+h)*T + l
    const int l = gid & (TT - 1);
    const int h = (gid >> 10) % HH;
    const int b = gid / (HH * TT);
    const int tid = threadIdx.x;

    __shared__ __align__(16) float q_s[DH];
    __shared__ float sc[TT];
    __shared__ float red[256];
    __shared__ float4 cpart[16][16];

    const float* Vb = V + (size_t)b * TT * DD + (size_t)h * DH;

    if (tid < DH) q_s[tid] = Q[((size_t)(b * TT + l)) * DD + h * DH + tid];
    __syncthreads();

    const int dg = tid & 15;   // d-chunk (4 floats)
    const int tg = tid >> 4;   // t subgroup 0..15
    float4 qv = *(const float4*)(q_s + dg * 4);

    // scores
    for (int it = 0; it < TT / 16; ++it) {
        int t = it * 16 + tg;
        float4 vv = *(const float4*)(Vb + (size_t)t * DD + dg * 4);
        float p = vv.x * qv.x + vv.y * qv.y + vv.z * qv.z + vv.w * qv.w;
        p += __shfl_down(p, 8, 16);
        p += __shfl_down(p, 4, 16);
        p += __shfl_down(p, 2, 16);
        p += __shfl_down(p, 1, 16);
        if (dg == 0) sc[t] = p * SCALE;
    }
    __syncthreads();

    // softmax over sc[0..1023]
    float m = -1e30f;
    for (int i = tid; i < TT; i += 256) m = fmaxf(m, sc[i]);
    red[tid] = m;
    __syncthreads();
    for (int off = 128; off > 0; off >>= 1) {
        if (tid < off) red[tid] = fmaxf(red[tid], red[tid + off]);
        __syncthreads();
    }
    m = red[0];
    __syncthreads();

    float s = 0.0f;
    for (int i = tid; i < TT; i += 256) {
        float e = expf(sc[i] - m);
        sc[i] = e;
        s += e;
    }
    red[tid] = s;
    __syncthreads();
    for (int off = 128; off > 0; off >>= 1) {
        if (tid < off) red[tid] += red[tid + off];
        __syncthreads();
    }
    float inv = 1.0f / red[0];
    __syncthreads();
    for (int i = tid; i < TT; i += 256) sc[i] *= inv;
    __syncthreads();

    // ctx = probs @ V_slice
    float4 acc = {0.f, 0.f, 0.f, 0.f};
    for (int t = tg; t < TT; t += 16) {
        float4 vv = *(const float4*)(Vb + (size_t)t * DD + dg * 4);
        float p = sc[t];
        acc.x += p * vv.x; acc.y += p * vv.y; acc.z += p * vv.z; acc.w += p * vv.w;
    }
    cpart[tg][dg] = acc;
    __syncthreads();
    if (tid < 16) {
        float4 r = cpart[0][tid];
#pragma unroll
        for (int i = 1; i < 16; ++i) {
            float4 c = cpart[i][tid];
            r.x += c.x; r.y += c.y; r.z += c.z; r.w += c.w;
        }
        *(float4*)(Ctx + ((size_t)(b * TT + l)) * DD + h * DH + tid * 4) = r;
    }
}

// ---------------------------------------------------------------------------
// Host launch
// ---------------------------------------------------------------------------
extern "C" void kernel_launch(void* const* d_in, const int* in_sizes, int n_in,
                              void* d_out, int out_size, void* d_ws, size_t ws_size,
                              hipStream_t stream) {
    const float* x_in  = (const float*)d_in[0];
    const float* ln1_g = (const float*)d_in[1];
    const float* ln1_b = (const float*)d_in[2];
    const float* Wq    = (const float*)d_in[3];
    const float* bq    = (const float*)d_in[4];
    const float* Wv    = (const float*)d_in[5];
    const float* bv    = (const float*)d_in[6];
    const float* Wo    = (const float*)d_in[7];
    const float* bo    = (const float*)d_in[8];
    const float* ln2_g = (const float*)d_in[9];
    const float* ln2_b = (const float*)d_in[10];
    const float* W1    = (const float*)d_in[11];
    const float* b1    = (const float*)d_in[12];
    const float* W2    = (const float*)d_in[13];
    const float* b2    = (const float*)d_in[14];

    float* x = (float*)d_out;                 // residual stream lives in d_out
    float* ws = (float*)d_ws;
    float* h   = ws;                          // M*D
    float* q   = h   + (size_t)MM * DD;       // M*D
    float* v   = q   + (size_t)MM * DD;       // M*D
    float* ctx = v   + (size_t)MM * DD;       // M*D
    float* h2  = ctx + (size_t)MM * DD;       // M*D
    float* a1  = h2  + (size_t)MM * DD;       // M*FF

    hipMemcpyAsync(x, x_in, (size_t)MM * DD * sizeof(float),
                   hipMemcpyDeviceToDevice, stream);

    const dim3 blk(256);
    const dim3 gemmD(DD / 64, MM / 64);   // N=768
    const dim3 gemmF(FF2 / 64, MM / 64);  // N=3072

    for (int l = 0; l < NL; ++l) {
        const float* Wq_l = Wq + (size_t)l * DD * DD;
        const float* Wv_l = Wv + (size_t)l * DD * DD;
        const float* Wo_l = Wo + (size_t)l * DD * DD;
        const float* W1_l = W1 + (size_t)l * DD * FF2;
        const float* W2_l = W2 + (size_t)l * FF2 * DD;

        ln_kernel<<<MM, blk, 0, stream>>>(x, ln1_g + l * DD, ln1_b + l * DD, h);

        gemm_kernel<0><<<gemmD, blk, 0, stream>>>(h, Wq_l, bq + l * DD, nullptr, q, MM, DD, DD);
        gemm_kernel<0><<<gemmD, blk, 0, stream>>>(h, Wv_l, bv + l * DD, nullptr, v, MM, DD, DD);

        attn_kernel<<<BB * HH * TT, blk, 0, stream>>>(q, v, ctx);

        // skip = x + ctx @ Wo + bo   (in-place on residual stream)
        gemm_kernel<1><<<gemmD, blk, 0, stream>>>(ctx, Wo_l, bo + l * DD, x, x, MM, DD, DD);

        ln_kernel<<<MM, blk, 0, stream>>>(x, ln2_g + l * DD, ln2_b + l * DD, h2);

        // a1 = gelu(h2 @ W1 + b1)
        gemm_kernel<2><<<gemmF, blk, 0, stream>>>(h2, W1_l, b1 + l * FF2, nullptr, a1, MM, FF2, DD);

        // x = x + a1 @ W2 + b2
        gemm_kernel<1><<<gemmD, blk, 0, stream>>>(a1, W2_l, b2 + l * DD, x, x, MM, DD, FF2);
    }
}

// Round 2
// 15366.266 us; speedup vs baseline: 1.5619x; 1.5619x over previous
//
#include <hip/hip_runtime.h>
#include <hip/hip_bf16.h>
#include <math.h>

// Problem constants (Encoder, D=768, H=12, L=12)
#define BB 4
#define TT 1024
#define DD 768
#define HH 12
#define DH 64
#define FF2 3072
#define NL 12
#define MM (BB * TT)            // 4096 rows
#define SCALE 0.03608439182435161f   // 768^-0.5
#define LN_EPS 1e-5f

// ---------------------------------------------------------------------------
// LayerNorm: one block per row of 768, 256 threads (3 elems/thread)
// ---------------------------------------------------------------------------
__global__ __launch_bounds__(256) void ln_kernel(const float* __restrict__ x,
                                                 const float* __restrict__ g,
                                                 const float* __restrict__ b,
                                                 float* __restrict__ out) {
    const int r = blockIdx.x;
    const int tid = threadIdx.x;
    const float* xr = x + (size_t)r * DD;
    float v0 = xr[tid], v1 = xr[tid + 256], v2 = xr[tid + 512];

    __shared__ float red[256];
    red[tid] = v0 + v1 + v2;
    __syncthreads();
    for (int off = 128; off > 0; off >>= 1) {
        if (tid < off) red[tid] += red[tid + off];
        __syncthreads();
    }
    float mu = red[0] * (1.0f / DD);
    __syncthreads();

    float d0 = v0 - mu, d1 = v1 - mu, d2 = v2 - mu;
    red[tid] = d0 * d0 + d1 * d1 + d2 * d2;
    __syncthreads();
    for (int off = 128; off > 0; off >>= 1) {
        if (tid < off) red[tid] += red[tid + off];
        __syncthreads();
    }
    float rstd = rsqrtf(red[0] * (1.0f / DD) + LN_EPS);

    float* outr = out + (size_t)r * DD;
    outr[tid]       = d0 * rstd * g[tid]       + b[tid];
    outr[tid + 256] = d1 * rstd * g[tid + 256] + b[tid + 256];
    outr[tid + 512] = d2 * rstd * g[tid + 512] + b[tid + 512];
}

// ---------------------------------------------------------------------------
// Tiled fp32 GEMM: C[M,N] = epi(A[M,K] @ W[K,N] + bias[N] (+ res[M,N]))
// 64x64 tile, BK=16, 256 threads, 4x4 micro-tile per thread.
// EPI: 0 = bias only, 1 = bias + residual add, 2 = bias + exact gelu
// ---------------------------------------------------------------------------
__device__ __forceinline__ float gelu_exact(float x) {
    return 0.5f * x * (1.0f + erff(x * 0.70710678118654752440f));
}

template <int EPI>
__global__ __launch_bounds__(256) void gemm_kernel(const float* __restrict__ A,
                                                   const float* __restrict__ W,
                                                   const float* __restrict__ bias,
                                                   const float* __restrict__ res,
                                                   float* __restrict__ C,
                                                   int M, int N, int K) {
    __shared__ float As[16][65];               // As[k][m], +1 pad
    __shared__ __align__(16) float Bs[16][64]; // Bs[k][n]

    const int tid = threadIdx.x;
    const int m0 = blockIdx.y * 64;
    const int n0 = blockIdx.x * 64;
    const int tx = tid & 15;    // n micro-tile
    const int ty = tid >> 4;    // m micro-tile

    // global-load assignments
    const int am = tid >> 2;          // 0..63 (row within A tile)
    const int ak = (tid & 3) * 4;     // 0,4,8,12
    const int wk = tid >> 4;          // 0..15 (row within W tile)
    const int wn = (tid & 15) * 4;    // 0..60

    const float* Aptr = A + (size_t)(m0 + am) * K + ak;
    const float* Wptr = W + (size_t)wk * N + (n0 + wn);

    float acc[4][4] = {};

    for (int k0 = 0; k0 < K; k0 += 16) {
        float4 a4 = *(const float4*)(Aptr + k0);
        float4 w4 = *(const float4*)(Wptr + (size_t)k0 * N);

        As[ak + 0][am] = a4.x;
        As[ak + 1][am] = a4.y;
        As[ak + 2][am] = a4.z;
        As[ak + 3][am] = a4.w;
        *(float4*)(&Bs[wk][wn]) = w4;
        __syncthreads();

#pragma unroll
        for (int k = 0; k < 16; ++k) {
            float a0 = As[k][ty * 4 + 0];
            float a1 = As[k][ty * 4 + 1];
            float a2 = As[k][ty * 4 + 2];
            float a3 = As[k][ty * 4 + 3];
            float4 b4 = *(const float4*)(&Bs[k][tx * 4]);
            acc[0][0] += a0 * b4.x; acc[0][1] += a0 * b4.y; acc[0][2] += a0 * b4.z; acc[0][3] += a0 * b4.w;
            acc[1][0] += a1 * b4.x; acc[1][1] += a1 * b4.y; acc[1][2] += a1 * b4.z; acc[1][3] += a1 * b4.w;
            acc[2][0] += a2 * b4.x; acc[2][1] += a2 * b4.y; acc[2][2] += a2 * b4.z; acc[2][3] += a2 * b4.w;
            acc[3][0] += a3 * b4.x; acc[3][1] += a3 * b4.y; acc[3][2] += a3 * b4.z; acc[3][3] += a3 * b4.w;
        }
        __syncthreads();
    }

    const int n = n0 + tx * 4;
    float4 bi = *(const float4*)(bias + n);
#pragma unroll
    for (int i = 0; i < 4; ++i) {
        const int m = m0 + ty * 4 + i;
        float4 c;
        c.x = acc[i][0] + bi.x;
        c.y = acc[i][1] + bi.y;
        c.z = acc[i][2] + bi.z;
        c.w = acc[i][3] + bi.w;
        if (EPI == 1) {
            float4 r = *(const float4*)(res + (size_t)m * N + n);
            c.x += r.x; c.y += r.y; c.z += r.z; c.w += r.w;
        }
        if (EPI == 2) {
            c.x = gelu_exact(c.x);
            c.y = gelu_exact(c.y);
            c.z = gelu_exact(c.z);
            c.w = gelu_exact(c.w);
        }
        *(float4*)(C + (size_t)m * N + n) = c;
    }
}

// ---------------------------------------------------------------------------
// Flash-style attention (quirky: scores = q . v). One block per
// (b, h, 64-query tile). 256 threads as 16x16; 4x4 micro-tiles.
// No running-max: scores are bounded (|s*SCALE| << 1), so accumulate
// exp(s) and row-sum directly; normalize at the end.
//   S phase: thread (ty,tx) owns queries ty*4+i, keys tx+16*j (strided ->
//            2-way-max LDS bank aliasing everywhere, free on CDNA4).
//   O phase: thread (ty,tx) owns queries ty*4+i, dims tx*4+j.
// LDS: Qs/Vs/Ps 64x68 fp32 = 52.2 KB -> 3 blocks/CU; grid 768 = 3/CU.
// ---------------------------------------------------------------------------
__global__ __launch_bounds__(256) void attn_flash(const float* __restrict__ Q,
                                                  const float* __restrict__ V,
                                                  float* __restrict__ Ctx) {
    const int qt = blockIdx.x & 15;
    const int h  = (blockIdx.x >> 4) % HH;
    const int b  = blockIdx.x / (16 * HH);
    const int tid = threadIdx.x;
    const int tx = tid & 15;
    const int ty = tid >> 4;

    __shared__ __align__(16) float Qs[64][68];
    __shared__ __align__(16) float Vs[64][68];
    __shared__ __align__(16) float Ps[64][68];

    const int q0 = qt * 64;
    const float* Qb = Q + ((size_t)(b * TT + q0)) * DD + h * DH;
    const float* Vb = V + ((size_t)b * TT) * DD + h * DH;

    // Load Q tile: 1024 float4-quads, 4 per thread. idx -> row=idx>>4, dq=idx&15
#pragma unroll
    for (int c = 0; c < 4; ++c) {
        int idx = tid + 256 * c;
        int row = idx >> 4, dq = idx & 15;
        float4 v4 = *(const float4*)(Qb + (size_t)row * DD + dq * 4);
        *(float4*)(&Qs[row][dq * 4]) = v4;
    }

    float O[4][4] = {};
    float lsum[4] = {};

    for (int t = 0; t < 16; ++t) {
        __syncthreads();   // prior O-phase done reading Vs/Ps (and Qs stores on t=0 half-covered)
#pragma unroll
        for (int c = 0; c < 4; ++c) {
            int idx = tid + 256 * c;
            int row = idx >> 4, dq = idx & 15;
            float4 v4 = *(const float4*)(Vb + (size_t)(t * 64 + row) * DD + dq * 4);
            *(float4*)(&Vs[row][dq * 4]) = v4;
        }
        __syncthreads();   // Vs (and, on t=0, Qs) ready

        // ---- S = Q . V^T over d ----
        float s[4][4] = {};
#pragma unroll
        for (int d0 = 0; d0 < 64; d0 += 4) {
            float4 qa[4], vb[4];
#pragma unroll
            for (int i = 0; i < 4; ++i) qa[i] = *(const float4*)(&Qs[ty * 4 + i][d0]);
#pragma unroll
            for (int j = 0; j < 4; ++j) vb[j] = *(const float4*)(&Vs[tx + 16 * j][d0]);
#pragma unroll
            for (int i = 0; i < 4; ++i)
#pragma unroll
                for (int j = 0; j < 4; ++j)
                    s[i][j] += qa[i].x * vb[j].x + qa[i].y * vb[j].y
                             + qa[i].z * vb[j].z + qa[i].w * vb[j].w;
        }

        // ---- P = exp(S*SCALE), accumulate row sums, stage P in LDS ----
#pragma unroll
        for (int i = 0; i < 4; ++i)
#pragma unroll
            for (int j = 0; j < 4; ++j) {
                float p = __expf(s[i][j] * SCALE);
                lsum[i] += p;
                Ps[ty * 4 + i][tx + 16 * j] = p;
            }
        __syncthreads();   // Ps ready

        // ---- O += P @ V ----
#pragma unroll
        for (int k0 = 0; k0 < 64; k0 += 4) {
            float4 pa[4], vb[4];
#pragma unroll
            for (int i = 0; i < 4; ++i) pa[i] = *(const float4*)(&Ps[ty * 4 + i][k0]);
#pragma unroll
            for (int kk = 0; kk < 4; ++kk) vb[kk] = *(const float4*)(&Vs[k0 + kk][tx * 4]);
#pragma unroll
            for (int i = 0; i < 4; ++i) {
                O[i][0] += pa[i].x * vb[0].x + pa[i].y * vb[1].x + pa[i].z * vb[2].x + pa[i].w * vb[3].x;
                O[i][1] += pa[i].x * vb[0].y + pa[i].y * vb[1].y + pa[i].z * vb[2].y + pa[i].w * vb[3].y;
                O[i][2] += pa[i].x * vb[0].z + pa[i].y * vb[1].z + pa[i].z * vb[2].z + pa[i].w * vb[3].z;
                O[i][3] += pa[i].x * vb[0].w + pa[i].y * vb[1].w + pa[i].z * vb[2].w + pa[i].w * vb[3].w;
            }
        }
    }
    __syncthreads();

    // ---- reduce lsum across tx (each thread saw 64 of 1024 keys per row) ----
#pragma unroll
    for (int i = 0; i < 4; ++i) Ps[ty * 4 + i][tx] = lsum[i];
    __syncthreads();

#pragma unroll
    for (int i = 0; i < 4; ++i) {
        float l = 0.0f;
#pragma unroll
        for (int t2 = 0; t2 < 16; ++t2) l += Ps[ty * 4 + i][t2];
        float inv = 1.0f / l;
        float4 o;
        o.x = O[i][0] * inv; o.y = O[i][1] * inv;
        o.z = O[i][2] * inv; o.w = O[i][3] * inv;
        *(float4*)(Ctx + ((size_t)(b * TT + q0 + ty * 4 + i)) * DD + h * DH + tx * 4) = o;
    }
}

// ---------------------------------------------------------------------------
// Host launch
// ---------------------------------------------------------------------------
extern "C" void kernel_launch(void* const* d_in, const int* in_sizes, int n_in,
                              void* d_out, int out_size, void* d_ws, size_t ws_size,
                              hipStream_t stream) {
    const float* x_in  = (const float*)d_in[0];
    const float* ln1_g = (const float*)d_in[1];
    const float* ln1_b = (const float*)d_in[2];
    const float* Wq    = (const float*)d_in[3];
    const float* bq    = (const float*)d_in[4];
    const float* Wv    = (const float*)d_in[5];
    const float* bv    = (const float*)d_in[6];
    const float* Wo    = (const float*)d_in[7];
    const float* bo    = (const float*)d_in[8];
    const float* ln2_g = (const float*)d_in[9];
    const float* ln2_b = (const float*)d_in[10];
    const float* W1    = (const float*)d_in[11];
    const float* b1    = (const float*)d_in[12];
    const float* W2    = (const float*)d_in[13];
    const float* b2    = (const float*)d_in[14];

    float* x = (float*)d_out;                 // residual stream lives in d_out
    float* ws = (float*)d_ws;
    float* h   = ws;                          // M*D
    float* q   = h   + (size_t)MM * DD;       // M*D
    float* v   = q   + (size_t)MM * DD;       // M*D
    float* ctx = v   + (size_t)MM * DD;       // M*D
    float* h2  = ctx + (size_t)MM * DD;       // M*D
    float* a1  = h2  + (size_t)MM * DD;       // M*FF

    hipMemcpyAsync(x, x_in, (size_t)MM * DD * sizeof(float),
                   hipMemcpyDeviceToDevice, stream);

    const dim3 blk(256);
    const dim3 gemmD(DD / 64, MM / 64);   // N=768
    const dim3 gemmF(FF2 / 64, MM / 64);  // N=3072

    for (int l = 0; l < NL; ++l) {
        const float* Wq_l = Wq + (size_t)l * DD * DD;
        const float* Wv_l = Wv + (size_t)l * DD * DD;
        const float* Wo_l = Wo + (size_t)l * DD * DD;
        const float* W1_l = W1 + (size_t)l * DD * FF2;
        const float* W2_l = W2 + (size_t)l * FF2 * DD;

        ln_kernel<<<MM, blk, 0, stream>>>(x, ln1_g + l * DD, ln1_b + l * DD, h);

        gemm_kernel<0><<<gemmD, blk, 0, stream>>>(h, Wq_l, bq + l * DD, nullptr, q, MM, DD, DD);
        gemm_kernel<0><<<gemmD, blk, 0, stream>>>(h, Wv_l, bv + l * DD, nullptr, v, MM, DD, DD);

        attn_flash<<<BB * HH * (TT / 64), blk, 0, stream>>>(q, v, ctx);

        // skip = x + ctx @ Wo + bo   (in-place on residual stream)
        gemm_kernel<1><<<gemmD, blk, 0, stream>>>(ctx, Wo_l, bo + l * DD, x, x, MM, DD, DD);

        ln_kernel<<<MM, blk, 0, stream>>>(x, ln2_g + l * DD, ln2_b + l * DD, h2);

        // a1 = gelu(h2 @ W1 + b1)
        gemm_kernel<2><<<gemmF, blk, 0, stream>>>(h2, W1_l, b1 + l * FF2, nullptr, a1, MM, FF2, DD);

        // x = x + a1 @ W2 + b2
        gemm_kernel<1><<<gemmD, blk, 0, stream>>>(a1, W2_l, b2 + l * DD, x, x, MM, DD, FF2);
    }
}

// Round 3
// 9456.857 us; speedup vs baseline: 2.5380x; 1.6249x over previous
//
#include <hip/hip_runtime.h>
#include <math.h>

// Problem constants (Encoder, D=768, H=12, L=12)
#define BB 4
#define TT 1024
#define DD 768
#define HH 12
#define DH 64
#define FF2 3072
#define NL 12
#define MM (BB * TT)            // 4096 rows
#define SCALE 0.03608439182435161f   // 768^-0.5
#define LN_EPS 1e-5f

typedef __attribute__((ext_vector_type(8))) short bf16x8;
typedef __attribute__((ext_vector_type(4))) float f32x4;

__device__ __forceinline__ ushort f2b(float x) {   // fp32 -> bf16 RNE
    uint u = __float_as_uint(x);
    uint r = (u + 0x7fffu + ((u >> 16) & 1u)) >> 16;
    return (ushort)r;
}
__device__ __forceinline__ float b2f(ushort h) { return __uint_as_float(((uint)h) << 16); }
__device__ __forceinline__ float blo(uint u) { return __uint_as_float(u << 16); }
__device__ __forceinline__ float bhi(uint u) { return __uint_as_float(u & 0xffff0000u); }

__device__ __forceinline__ float gelu_exact(float x) {
    return 0.5f * x * (1.0f + erff(x * 0.70710678118654752440f));
}

// XOR-swizzled 16B-chunk index for a [rows][32] bf16 tile:
// data (row r, k-chunk q of 8 bf16) lives at chunk 4r + (q ^ (r&3) ^ ((r>>2)&3)).
// Reads (16 rows per quad) hit each bank-residue exactly 2x (free);
// staging writes are a lane-contiguous permutation (conflict-free).
__device__ __forceinline__ int swz(int r, int q) {
    return 4 * r + ((q ^ (r & 3) ^ ((r >> 2) & 3)) & 3);
}

// ---------------------------------------------------------------------------
// LayerNorm: one block per row of 768, 256 threads; bf16 output
// ---------------------------------------------------------------------------
__global__ __launch_bounds__(256) void ln_kernel(const float* __restrict__ x,
                                                 const float* __restrict__ g,
                                                 const float* __restrict__ b,
                                                 ushort* __restrict__ out) {
    const int r = blockIdx.x;
    const int tid = threadIdx.x;
    const float* xr = x + (size_t)r * DD;
    float v0 = xr[tid], v1 = xr[tid + 256], v2 = xr[tid + 512];

    __shared__ float red[256];
    red[tid] = v0 + v1 + v2;
    __syncthreads();
    for (int off = 128; off > 0; off >>= 1) {
        if (tid < off) red[tid] += red[tid + off];
        __syncthreads();
    }
    float mu = red[0] * (1.0f / DD);
    __syncthreads();

    float d0 = v0 - mu, d1 = v1 - mu, d2 = v2 - mu;
    red[tid] = d0 * d0 + d1 * d1 + d2 * d2;
    __syncthreads();
    for (int off = 128; off > 0; off >>= 1) {
        if (tid < off) red[tid] += red[tid + off];
        __syncthreads();
    }
    float rstd = rsqrtf(red[0] * (1.0f / DD) + LN_EPS);

    ushort* outr = out + (size_t)r * DD;
    outr[tid]       = f2b(d0 * rstd * g[tid]       + b[tid]);
    outr[tid + 256] = f2b(d1 * rstd * g[tid + 256] + b[tid + 256]);
    outr[tid + 512] = f2b(d2 * rstd * g[tid + 512] + b[tid + 512]);
}

// ---------------------------------------------------------------------------
// Transpose + fp32->bf16 convert: W[R][C] -> Wt[C][R].  block (32,8)
// ---------------------------------------------------------------------------
__global__ __launch_bounds__(256) void tconv(const float* __restrict__ W,
                                             ushort* __restrict__ Wt,
                                             int R, int C) {
    __shared__ float t[32][33];
    const int tx = threadIdx.x, ty = threadIdx.y;
    const int gr = blockIdx.y * 32, gc = blockIdx.x * 32;
#pragma unroll
    for (int i = 0; i < 4; ++i)
        t[ty + 8 * i][tx] = W[(size_t)(gr + ty + 8 * i) * C + gc + tx];
    __syncthreads();
#pragma unroll
    for (int i = 0; i < 4; ++i)
        Wt[(size_t)(gc + ty + 8 * i) * R + gr + tx] = f2b(t[tx][ty + 8 * i]);
}

// ---------------------------------------------------------------------------
// MFMA bf16 GEMM: C[M,N] = epi(A[M,K] @ Wt[N,K]^T + bias[N] (+ res fp32))
// BM=128, BK=32, 256 threads (4 waves).
//   BN=128: waves 2x2, each 64x64 (4x4 MFMAs of 16x16x32)
//   BN= 64: waves 4x1, each 32x64 (2x4 MFMAs)
// EPI: 0 = bias, 1 = bias + fp32 residual (fp32 out), 2 = bias + gelu
// ---------------------------------------------------------------------------
template <int BN, int EPI, bool OBF16>
__global__ __launch_bounds__(256) void mfma_gemm(const ushort* __restrict__ A,
                                                 const ushort* __restrict__ Wt,
                                                 const float* __restrict__ bias,
                                                 const float* __restrict__ res,
                                                 void* __restrict__ Cout,
                                                 int M, int N, int K) {
    constexpr int BM = 128;
    constexpr int ACH = BM * 4;             // 16B chunks in A tile
    constexpr int BCH = BN * 4;
    constexpr int PT = (ACH + BCH) / 256;   // chunks per thread
    constexpr int NI = (BN == 128) ? 4 : 2;
    constexpr int NJ = 4;

    __shared__ ushort As[BM * 32];
    __shared__ ushort Bs[BN * 32];

    const int tid = threadIdx.x;
    const int lane = tid & 63, wave = tid >> 6;
    const int wm = (BN == 128) ? (wave & 1) * 64 : wave * 32;
    const int wn = (BN == 128) ? (wave >> 1) * 64 : 0;
    const int m0 = blockIdx.y * BM, n0 = blockIdx.x * BN;

    f32x4 acc[NI][NJ];
#pragma unroll
    for (int i = 0; i < NI; ++i)
#pragma unroll
        for (int j = 0; j < NJ; ++j) acc[i][j] = (f32x4){0.f, 0.f, 0.f, 0.f};

    // staging assignments (chunk -> global source, LDS dest)
    const ushort* gsrc[PT];
    ushort* ldst[PT];
#pragma unroll
    for (int s = 0; s < PT; ++s) {
        int c = tid + 256 * s;
        if (c < ACH) {
            int r = c >> 2, qs = c & 3;
            int ql = qs ^ (r & 3) ^ ((r >> 2) & 3);
            gsrc[s] = A + (size_t)(m0 + r) * K + ql * 8;
            ldst[s] = As + c * 8;
        } else {
            int cb = c - ACH;
            int r = cb >> 2, qs = cb & 3;
            int ql = qs ^ (r & 3) ^ ((r >> 2) & 3);
            gsrc[s] = Wt + (size_t)(n0 + r) * K + ql * 8;
            ldst[s] = Bs + cb * 8;
        }
    }

    // per-lane fragment LDS chunk indices
    const int q = lane >> 4;
    int ca[NI], cb[NJ];
#pragma unroll
    for (int i = 0; i < NI; ++i) { int r = wm + i * 16 + (lane & 15); ca[i] = swz(r, q); }
#pragma unroll
    for (int j = 0; j < NJ; ++j) { int r = wn + j * 16 + (lane & 15); cb[j] = swz(r, q); }

    for (int k0 = 0; k0 < K; k0 += 32) {
        uint4 tmp[PT];
#pragma unroll
        for (int s = 0; s < PT; ++s) tmp[s] = *(const uint4*)(gsrc[s] + k0);
        __syncthreads();   // previous iter's frag reads done
#pragma unroll
        for (int s = 0; s < PT; ++s) *(uint4*)(ldst[s]) = tmp[s];
        __syncthreads();   // tiles ready

        bf16x8 af[NI], bfr[NJ];
#pragma unroll
        for (int i = 0; i < NI; ++i) af[i] = *(const bf16x8*)(As + ca[i] * 8);
#pragma unroll
        for (int j = 0; j < NJ; ++j) bfr[j] = *(const bf16x8*)(Bs + cb[j] * 8);
#pragma unroll
        for (int i = 0; i < NI; ++i)
#pragma unroll
            for (int j = 0; j < NJ; ++j)
                acc[i][j] = __builtin_amdgcn_mfma_f32_16x16x32_bf16(af[i], bfr[j], acc[i][j], 0, 0, 0);
    }

    // epilogue: D col = lane&15, row = (lane>>4)*4 + reg
    const int col = lane & 15, rq = (lane >> 4) * 4;
#pragma unroll
    for (int j = 0; j < NJ; ++j) {
        const int n = n0 + wn + j * 16 + col;
        const float bj = bias[n];
#pragma unroll
        for (int i = 0; i < NI; ++i) {
#pragma unroll
            for (int r4 = 0; r4 < 4; ++r4) {
                const int m = m0 + wm + i * 16 + rq + r4;
                float v = acc[i][j][r4] + bj;
                if (EPI == 1) v += res[(size_t)m * N + n];
                if (EPI == 2) v = gelu_exact(v);
                if (OBF16) ((ushort*)Cout)[(size_t)m * N + n] = f2b(v);
                else       ((float*)Cout)[(size_t)m * N + n] = v;
            }
        }
    }
}

// ---------------------------------------------------------------------------
// Flash-style attention (quirky: scores = q . v), bf16 Q/V/Ctx, fp32 inside.
// One block per (b, h, 64-query tile); 256 threads as 16x16.
// ---------------------------------------------------------------------------
__global__ __launch_bounds__(256) void attn_flash(const ushort* __restrict__ Q,
                                                  const ushort* __restrict__ V,
                                                  ushort* __restrict__ Ctx) {
    const int qt = blockIdx.x & 15;
    const int h  = (blockIdx.x >> 4) % HH;
    const int b  = blockIdx.x / (16 * HH);
    const int tid = threadIdx.x;
    const int tx = tid & 15;
    const int ty = tid >> 4;

    __shared__ __align__(16) float Qs[64][68];
    __shared__ __align__(16) float Vs[64][68];
    __shared__ __align__(16) float Ps[64][68];

    const int q0 = qt * 64;
    const ushort* Qb = Q + ((size_t)(b * TT + q0)) * DD + h * DH;
    const ushort* Vb = V + ((size_t)b * TT) * DD + h * DH;

    // Load Q tile: 512 chunks of 8 bf16; 2 per thread
#pragma unroll
    for (int c = 0; c < 2; ++c) {
        int idx = tid + 256 * c;
        int row = idx >> 3, d8 = idx & 7;
        uint4 u = *(const uint4*)(Qb + (size_t)row * DD + d8 * 8);
        float4 f0 = {blo(u.x), bhi(u.x), blo(u.y), bhi(u.y)};
        float4 f1 = {blo(u.z), bhi(u.z), blo(u.w), bhi(u.w)};
        *(float4*)(&Qs[row][d8 * 8])     = f0;
        *(float4*)(&Qs[row][d8 * 8 + 4]) = f1;
    }

    float O[4][4] = {};
    float lsum[4] = {};

    for (int t = 0; t < 16; ++t) {
        __syncthreads();
#pragma unroll
        for (int c = 0; c < 2; ++c) {
            int idx = tid + 256 * c;
            int row = idx >> 3, d8 = idx & 7;
            uint4 u = *(const uint4*)(Vb + (size_t)(t * 64 + row) * DD + d8 * 8);
            float4 f0 = {blo(u.x), bhi(u.x), blo(u.y), bhi(u.y)};
            float4 f1 = {blo(u.z), bhi(u.z), blo(u.w), bhi(u.w)};
            *(float4*)(&Vs[row][d8 * 8])     = f0;
            *(float4*)(&Vs[row][d8 * 8 + 4]) = f1;
        }
        __syncthreads();

        // ---- S = Q . V^T over d ----
        float s[4][4] = {};
#pragma unroll
        for (int d0 = 0; d0 < 64; d0 += 4) {
            float4 qa[4], vb[4];
#pragma unroll
            for (int i = 0; i < 4; ++i) qa[i] = *(const float4*)(&Qs[ty * 4 + i][d0]);
#pragma unroll
            for (int j = 0; j < 4; ++j) vb[j] = *(const float4*)(&Vs[tx + 16 * j][d0]);
#pragma unroll
            for (int i = 0; i < 4; ++i)
#pragma unroll
                for (int j = 0; j < 4; ++j)
                    s[i][j] += qa[i].x * vb[j].x + qa[i].y * vb[j].y
                             + qa[i].z * vb[j].z + qa[i].w * vb[j].w;
        }

        // ---- P = exp(S*SCALE) (bounded scores: no max subtraction) ----
#pragma unroll
        for (int i = 0; i < 4; ++i)
#pragma unroll
            for (int j = 0; j < 4; ++j) {
                float p = __expf(s[i][j] * SCALE);
                lsum[i] += p;
                Ps[ty * 4 + i][tx + 16 * j] = p;
            }
        __syncthreads();

        // ---- O += P @ V ----
#pragma unroll
        for (int k0 = 0; k0 < 64; k0 += 4) {
            float4 pa[4], vb[4];
#pragma unroll
            for (int i = 0; i < 4; ++i) pa[i] = *(const float4*)(&Ps[ty * 4 + i][k0]);
#pragma unroll
            for (int kk = 0; kk < 4; ++kk) vb[kk] = *(const float4*)(&Vs[k0 + kk][tx * 4]);
#pragma unroll
            for (int i = 0; i < 4; ++i) {
                O[i][0] += pa[i].x * vb[0].x + pa[i].y * vb[1].x + pa[i].z * vb[2].x + pa[i].w * vb[3].x;
                O[i][1] += pa[i].x * vb[0].y + pa[i].y * vb[1].y + pa[i].z * vb[2].y + pa[i].w * vb[3].y;
                O[i][2] += pa[i].x * vb[0].z + pa[i].y * vb[1].z + pa[i].z * vb[2].z + pa[i].w * vb[3].z;
                O[i][3] += pa[i].x * vb[0].w + pa[i].y * vb[1].w + pa[i].z * vb[2].w + pa[i].w * vb[3].w;
            }
        }
    }
    __syncthreads();

    // ---- reduce lsum across tx, normalize, write bf16 ----
#pragma unroll
    for (int i = 0; i < 4; ++i) Ps[ty * 4 + i][tx] = lsum[i];
    __syncthreads();

#pragma unroll
    for (int i = 0; i < 4; ++i) {
        float l = 0.0f;
#pragma unroll
        for (int t2 = 0; t2 < 16; ++t2) l += Ps[ty * 4 + i][t2];
        float inv = 1.0f / l;
        ushort4 o;
        o.x = f2b(O[i][0] * inv); o.y = f2b(O[i][1] * inv);
        o.z = f2b(O[i][2] * inv); o.w = f2b(O[i][3] * inv);
        *(ushort4*)(Ctx + ((size_t)(b * TT + q0 + ty * 4 + i)) * DD + h * DH + tx * 4) = o;
    }
}

// ---------------------------------------------------------------------------
// Host launch
// ---------------------------------------------------------------------------
extern "C" void kernel_launch(void* const* d_in, const int* in_sizes, int n_in,
                              void* d_out, int out_size, void* d_ws, size_t ws_size,
                              hipStream_t stream) {
    const float* x_in  = (const float*)d_in[0];
    const float* ln1_g = (const float*)d_in[1];
    const float* ln1_b = (const float*)d_in[2];
    const float* Wq    = (const float*)d_in[3];
    const float* bq    = (const float*)d_in[4];
    const float* Wv    = (const float*)d_in[5];
    const float* bv    = (const float*)d_in[6];
    const float* Wo    = (const float*)d_in[7];
    const float* bo    = (const float*)d_in[8];
    const float* ln2_g = (const float*)d_in[9];
    const float* ln2_b = (const float*)d_in[10];
    const float* W1    = (const float*)d_in[11];
    const float* b1    = (const float*)d_in[12];
    const float* W2    = (const float*)d_in[13];
    const float* b2    = (const float*)d_in[14];

    float* x = (float*)d_out;                 // residual stream (fp32)
    ushort* h   = (ushort*)d_ws;              // M*D bf16
    ushort* qb  = h   + (size_t)MM * DD;
    ushort* vb  = qb  + (size_t)MM * DD;
    ushort* ctx = vb  + (size_t)MM * DD;
    ushort* h2  = ctx + (size_t)MM * DD;
    ushort* a1  = h2  + (size_t)MM * DD;      // M*FF bf16
    ushort* Wtq = a1  + (size_t)MM * FF2;
    ushort* Wtv = Wtq + (size_t)DD * DD;
    ushort* Wto = Wtv + (size_t)DD * DD;
    ushort* Wt1 = Wto + (size_t)DD * DD;      // [FF][D]
    ushort* Wt2 = Wt1 + (size_t)DD * FF2;     // [D][FF]

    hipMemcpyAsync(x, x_in, (size_t)MM * DD * sizeof(float),
                   hipMemcpyDeviceToDevice, stream);

    const dim3 blk(256);
    const dim3 t32(32, 8);
    const dim3 gD(12, 32);    // N=768, BN=64
    const dim3 gF(24, 32);    // N=3072, BN=128

    for (int l = 0; l < NL; ++l) {
        const float* Wq_l = Wq + (size_t)l * DD * DD;
        const float* Wv_l = Wv + (size_t)l * DD * DD;
        const float* Wo_l = Wo + (size_t)l * DD * DD;
        const float* W1_l = W1 + (size_t)l * DD * FF2;
        const float* W2_l = W2 + (size_t)l * FF2 * DD;

        tconv<<<dim3(24, 24), t32, 0, stream>>>(Wq_l, Wtq, DD, DD);
        tconv<<<dim3(24, 24), t32, 0, stream>>>(Wv_l, Wtv, DD, DD);
        tconv<<<dim3(24, 24), t32, 0, stream>>>(Wo_l, Wto, DD, DD);
        tconv<<<dim3(96, 24), t32, 0, stream>>>(W1_l, Wt1, DD, FF2);
        tconv<<<dim3(24, 96), t32, 0, stream>>>(W2_l, Wt2, FF2, DD);

        ln_kernel<<<MM, blk, 0, stream>>>(x, ln1_g + l * DD, ln1_b + l * DD, h);

        mfma_gemm<64, 0, true><<<gD, blk, 0, stream>>>(h, Wtq, bq + l * DD, nullptr, qb, MM, DD, DD);
        mfma_gemm<64, 0, true><<<gD, blk, 0, stream>>>(h, Wtv, bv + l * DD, nullptr, vb, MM, DD, DD);

        attn_flash<<<BB * HH * (TT / 64), blk, 0, stream>>>(qb, vb, ctx);

        // x = x + ctx @ Wo + bo (fp32 residual)
        mfma_gemm<64, 1, false><<<gD, blk, 0, stream>>>(ctx, Wto, bo + l * DD, x, x, MM, DD, DD);

        ln_kernel<<<MM, blk, 0, stream>>>(x, ln2_g + l * DD, ln2_b + l * DD, h2);

        // a1 = gelu(h2 @ W1 + b1)
        mfma_gemm<128, 2, true><<<gF, blk, 0, stream>>>(h2, Wt1, b1 + l * FF2, nullptr, a1, MM, FF2, DD);

        // x = x + a1 @ W2 + b2
        mfma_gemm<64, 1, false><<<gD, blk, 0, stream>>>(a1, Wt2, b2 + l * DD, x, x, MM, DD, FF2);
    }
}